// Round 4
// baseline (313.184 us; speedup 1.0000x reference)
//
#include <hip/hip_runtime.h>

// Tensor Fusion Network, MI355X. Round 4.
// k1: fusion[b][p] bf16 (p = ij*97+k); A-frag (w = a*v) built directly in
//     registers from transposed LDS a/v; barrier-free main loop.
// k2: split-K GEMM with explicit register double-buffer (prefetch next K-step
//     while MFMAing current). No LDS, no barriers, no guards except tail block.
// k3: parallel reduce + bias + relu. k45: fused MLP tail.

#define B_    128
#define T_    64
#define A1    49
#define V1    49
#define X1    97
#define IJ    2401      // 49*49
#define KTOT  232897    // IJ*97
#define FP    232928    // KTOT padded to multiple of 32
#define PF    128
#define KC    512       // K-chunk per k2 block
#define NB2   455       // ceil(FP/KC)
#define NTILES 151      // ceil(IJ/16)

typedef short s8v __attribute__((ext_vector_type(8)));   // 8 bf16
typedef float f4v __attribute__((ext_vector_type(4)));   // 4 fp32

__device__ __forceinline__ unsigned short f2bf(float f) {
    union { float f; unsigned u; } v; v.f = f;
    return (unsigned short)((v.u + 0x7FFFu + ((v.u >> 16) & 1u)) >> 16); // RNE
}

// ---------------- k1: fusion (bf16) -------------------------------------
// grid (8, 128): blockIdx.y = b, blockIdx.x covers 19 ij-tiles of 16.
// 256 threads = 4 waves, wave-private tiles, no barriers after staging.
__global__ __launch_bounds__(256) void k1_fusion(
    const float* __restrict__ audio, const float* __restrict__ video,
    const float* __restrict__ text, unsigned short* __restrict__ fusion)
{
    __shared__ float aT[49 * 68];                  // [i][t], pad 68
    __shared__ float vT[49 * 68];                  // [j][t], pad 68
    __shared__ unsigned short xT[112 * 72];        // [k][t], pad 72

    const int b = blockIdx.y;
    const int bx = blockIdx.x;
    const int tid = threadIdx.x;

    for (int idx = tid; idx < 49 * 64; idx += 256) {
        int i = idx >> 6, t = idx & 63;
        aT[i * 68 + t] = (i == 0) ? 1.0f : audio[(b * 64 + t) * 48 + (i - 1)];
        vT[i * 68 + t] = (i == 0) ? 1.0f : video[(b * 64 + t) * 48 + (i - 1)];
    }
    for (int idx = tid; idx < 64 * 97; idx += 256) {
        int t = idx / 97, k = idx - t * 97;
        xT[k * 72 + t] = f2bf((k == 0) ? 1.0f : text[(b * 64 + t) * 96 + (k - 1)]);
    }
    for (int idx = tid; idx < 15 * 64; idx += 256)   // zero pad rows k=97..111
        xT[(97 + (idx >> 6)) * 72 + (idx & 63)] = 0;
    __syncthreads();

    const int wave = tid >> 6, lane = tid & 63;
    const int q = lane >> 4, ln = lane & 15;

    #pragma unroll
    for (int it = 0; it < 5; ++it) {
        const int tw = it * 4 + wave;
        const int tl = bx * 19 + tw;
        if (tw >= 19 || tl >= NTILES) continue;    // wave-uniform
        const int ij0 = tl * 16;

        const int ij = ij0 + ln;
        const bool valid = ij < IJ;
        const int ijc = valid ? ij : IJ - 1;
        const int i = ijc / 49, j2 = ijc - i * 49;
        const float* ar = &aT[i * 68 + q * 8];
        const float* vr = &vT[j2 * 68 + q * 8];

        s8v af0, af1;
        #pragma unroll
        for (int j = 0; j < 8; ++j) {
            float w0 = ar[j] * vr[j];
            float w1 = ar[32 + j] * vr[32 + j];
            ((unsigned short*)&af0)[j] = valid ? f2bf(w0) : (unsigned short)0;
            ((unsigned short*)&af1)[j] = valid ? f2bf(w1) : (unsigned short)0;
        }

        #pragma unroll
        for (int nt = 0; nt < 7; ++nt) {
            s8v bf0 = *(const s8v*)&xT[(nt * 16 + ln) * 72 + q * 8];
            s8v bf1 = *(const s8v*)&xT[(nt * 16 + ln) * 72 + 32 + q * 8];
            f4v acc = {0.f, 0.f, 0.f, 0.f};
            acc = __builtin_amdgcn_mfma_f32_16x16x32_bf16(af0, bf0, acc, 0, 0, 0);
            acc = __builtin_amdgcn_mfma_f32_16x16x32_bf16(af1, bf1, acc, 0, 0, 0);
            int kk = nt * 16 + ln;             // C: col=ln -> k, row=q*4+r -> ij
            if (kk < X1) {
                #pragma unroll
                for (int r = 0; r < 4; ++r) {
                    int ijr = ij0 + q * 4 + r;
                    if (ijr < IJ)
                        fusion[(size_t)b * FP + ijr * X1 + kk] = f2bf(acc[r]);
                }
            }
        }
    }
}

// ---------------- k2: split-K GEMM, register-pipelined ------------------
// 455 blocks x 512 thr (8 waves). Wave owns f-tile = wave*16, all M=128.
// Per K-step(32): 8 A-frags (dwordx4 fusion) + 8 B-dwords (W1) prefetched
// one step ahead in registers. No LDS, no barriers.
template<int NSTEPS, bool GUARD>
__device__ __forceinline__ void k2_body(
    const unsigned short* __restrict__ fusion, const float* __restrict__ W1,
    float* __restrict__ partials, int blk)
{
    const int kbase = blk * KC;
    const int tid = threadIdx.x;
    const int wave = tid >> 6, lane = tid & 63;
    const int q = lane >> 4, ln = lane & 15;
    const int f = wave * 16 + ln;

    f4v acc[8];
    #pragma unroll
    for (int m = 0; m < 8; ++m) acc[m] = (f4v){0.f, 0.f, 0.f, 0.f};

    s8v a_cur[8], a_nxt[8];
    float bw_cur[8], bw_nxt[8];

    // prefetch step 0 (step 0 is never the guarded step when NSTEPS>1)
    #pragma unroll
    for (int j = 0; j < 8; ++j)
        bw_cur[j] = __builtin_nontemporal_load(
            &W1[(size_t)(kbase + q * 8 + j) * PF + f]);
    #pragma unroll
    for (int m = 0; m < 8; ++m)
        a_cur[m] = *(const s8v*)&fusion[(size_t)(m * 16 + ln) * FP + kbase + q * 8];

    #pragma unroll
    for (int s = 0; s < NSTEPS; ++s) {
        if (s + 1 < NSTEPS) {
            const int p0 = kbase + (s + 1) * 32 + q * 8;
            if (GUARD && (s + 1 == NSTEPS - 1)) {
                #pragma unroll
                for (int j = 0; j < 8; ++j)
                    bw_nxt[j] = (p0 + j < KTOT) ? W1[(size_t)(p0 + j) * PF + f] : 0.f;
            } else {
                #pragma unroll
                for (int j = 0; j < 8; ++j)
                    bw_nxt[j] = __builtin_nontemporal_load(&W1[(size_t)(p0 + j) * PF + f]);
            }
            #pragma unroll
            for (int m = 0; m < 8; ++m)
                a_nxt[m] = *(const s8v*)&fusion[(size_t)(m * 16 + ln) * FP +
                                                kbase + (s + 1) * 32 + q * 8];
        }
        s8v bf;
        #pragma unroll
        for (int j = 0; j < 8; ++j)
            ((unsigned short*)&bf)[j] = f2bf(bw_cur[j]);
        #pragma unroll
        for (int m = 0; m < 8; ++m)
            acc[m] = __builtin_amdgcn_mfma_f32_16x16x32_bf16(a_cur[m], bf, acc[m], 0, 0, 0);
        #pragma unroll
        for (int m = 0; m < 8; ++m) a_cur[m] = a_nxt[m];
        #pragma unroll
        for (int j = 0; j < 8; ++j) bw_cur[j] = bw_nxt[j];
    }

    float* outp = partials + (size_t)blk * 16384;
    #pragma unroll
    for (int m = 0; m < 8; ++m)
        #pragma unroll
        for (int r = 0; r < 4; ++r)
            outp[(m * 16 + q * 4 + r) * 128 + f] = acc[m][r];
}

__global__ __launch_bounds__(512, 4) void k2_gemm(
    const unsigned short* __restrict__ fusion, const float* __restrict__ W1,
    float* __restrict__ partials)
{
    const int blk = blockIdx.x;
    // tail block: kbase=232448; 15 steps reach exactly FP=232928 (buffer edge),
    // step 14 guards W1 at KTOT. Blocks 0..453: 16 unguarded steps.
    if (blk == NB2 - 1) k2_body<15, true>(fusion, W1, partials, blk);
    else                k2_body<16, false>(fusion, W1, partials, blk);
}

// ---------------- k3: reduce partials + bias + relu ---------------------
// 512 blocks x 256 thr: block owns 32 e-values, 8-way r-split per e.
__global__ __launch_bounds__(256) void k3_reduce(
    const float* __restrict__ partials, const float* __restrict__ b1,
    float* __restrict__ h1)
{
    __shared__ float red[256];
    const int e = blockIdx.x * 32 + (threadIdx.x & 31);
    const int rh = threadIdx.x >> 5;           // 0..7
    float s0 = 0.f, s1 = 0.f;
    int r = rh;
    for (; r + 8 < NB2; r += 16) {
        s0 += partials[(size_t)r * 16384 + e];
        s1 += partials[(size_t)(r + 8) * 16384 + e];
    }
    for (; r < NB2; r += 8) s0 += partials[(size_t)r * 16384 + e];
    red[threadIdx.x] = s0 + s1;
    __syncthreads();
    if (threadIdx.x < 32) {
        float v = 0.f;
        #pragma unroll
        for (int g = 0; g < 8; ++g) v += red[g * 32 + threadIdx.x];
        v += b1[e & 127];
        h1[e] = fmaxf(v, 0.f);
    }
}

// ---------------- k45: out = sigmoid(relu(h1@W2+b2)@W3 + b3)*6 - 3 ------
__global__ __launch_bounds__(128) void k45_tail(
    const float* __restrict__ h1, const float* __restrict__ W2,
    const float* __restrict__ b2, const float* __restrict__ W3,
    const float* __restrict__ b3, float* __restrict__ out)
{
    __shared__ float hrow[128];
    __shared__ float h2s[128];
    const int b = blockIdx.x, f = threadIdx.x;
    hrow[f] = h1[b * 128 + f];
    __syncthreads();
    float s = b2[f];
    #pragma unroll 8
    for (int c = 0; c < 128; ++c) s += hrow[c] * W2[c * 128 + f];
    h2s[f] = fmaxf(s, 0.f) * W3[f];
    __syncthreads();
    if (f < 64) {
        float v = h2s[f] + h2s[f + 64];
        #pragma unroll
        for (int off = 32; off > 0; off >>= 1)
            v += __shfl_down(v, off, 64);
        if (f == 0) out[b] = 6.0f / (1.0f + expf(-(v + b3[0]))) - 3.0f;
    }
}

extern "C" void kernel_launch(void* const* d_in, const int* in_sizes, int n_in,
                              void* d_out, int out_size, void* d_ws, size_t ws_size,
                              hipStream_t stream)
{
    const float* audio = (const float*)d_in[0];
    const float* video = (const float*)d_in[1];
    const float* text  = (const float*)d_in[2];
    const float* W1 = (const float*)d_in[3];
    const float* b1 = (const float*)d_in[4];
    const float* W2 = (const float*)d_in[5];
    const float* b2 = (const float*)d_in[6];
    const float* W3 = (const float*)d_in[7];
    const float* b3 = (const float*)d_in[8];
    float* out = (float*)d_out;

    // ws layout (bytes):
    //   fusion bf16 [128][FP]       @ 0          = 59,629,568
    //   partials fp32 [455][16384]  @ 59,629,568 = 29,818,880
    //   h1 fp32 [16384]             @ 89,448,448
    char* ws = (char*)d_ws;
    unsigned short* fusion = (unsigned short*)ws;
    float* partials = (float*)(ws + 59629568);
    float* h1 = (float*)(ws + 89448448);

    k1_fusion<<<dim3(8, 128), 256, 0, stream>>>(audio, video, text, fusion);
    k2_gemm<<<dim3(NB2), 512, 0, stream>>>(fusion, W1, partials);
    k3_reduce<<<dim3(512), 256, 0, stream>>>(partials, b1, h1);
    k45_tail<<<dim3(128), 128, 0, stream>>>(h1, W2, b2, W3, b3, out);
}

// Round 5
// 277.835 us; speedup vs baseline: 1.1272x; 1.1272x over previous
//
#include <hip/hip_runtime.h>

// Tensor Fusion Network, MI355X. Round 5.
// fusionT layout: [pstep][b][kin]  (p = ij*97+kk, pstep=p/32, kin=p%32).
//   -> k2's A-frag loads are contiguous 1KB per wave-instruction.
// k1: block = (b, 128-ij group); 8 waves MFMA one 16-ij tile each into LDS
//     out_s[128x97], then block drains to fusionT with dwordx4 stores
//     (group p-range is exactly 388 aligned 32-chunks since 128*97 % 32 == 0).
// k2: split-K GEMM, LDS-free, coalesced A, register prefetch.
// k3: parallel reduce + bias + relu. k45: fused MLP tail.

#define B_    128
#define T_    64
#define X1    97
#define IJ    2401      // 49*49
#define KTOT  232897    // IJ*97
#define PF    128
#define NGRP  19        // ij groups of 128 (19*128 = 2432 ij incl. 31 zero rows)
#define PSTEPS 7376     // fusionT capacity in 32-p steps (= 461*16)
#define KC    512       // 16 psteps per k2 block
#define NB2   461       // PSTEPS/16

typedef short s8v __attribute__((ext_vector_type(8)));   // 8 bf16
typedef float f4v __attribute__((ext_vector_type(4)));   // 4 fp32
typedef unsigned short u8sv __attribute__((ext_vector_type(8), aligned(16)));

__device__ __forceinline__ unsigned short f2bf(float f) {
    union { float f; unsigned u; } v; v.f = f;
    return (unsigned short)((v.u + 0x7FFFu + ((v.u >> 16) & 1u)) >> 16); // RNE
}

// ---------------- k1: fusionT (bf16, tiled) -----------------------------
// grid (NGRP, 128): blockIdx.y = b, blockIdx.x = g (128-ij group). 512 thr.
__global__ __launch_bounds__(512) void k1_fusion(
    const float* __restrict__ audio, const float* __restrict__ video,
    const float* __restrict__ text, unsigned short* __restrict__ fusionT)
{
    __shared__ float aT[49 * 68];                    // [i][t]
    __shared__ float vT[49 * 68];                    // [j][t]
    __shared__ unsigned short xT[112 * 72];          // [k][t] bf16, rows 97..111 zero
    __shared__ __align__(16) unsigned short out_s[128 * 97];  // [ij_local][kk]

    const int b = blockIdx.y;
    const int g = blockIdx.x;
    const int tid = threadIdx.x;

    // stage audio/video transposed [feat][t] (float4 global loads)
    for (int idx = tid; idx < 768; idx += 512) {     // 64 t * 12 float4
        int t = idx / 12, c = idx - t * 12;
        float4 av = *(const float4*)&audio[(b * 64 + t) * 48 + c * 4];
        float4 vv = *(const float4*)&video[(b * 64 + t) * 48 + c * 4];
        aT[(1 + c * 4 + 0) * 68 + t] = av.x; aT[(1 + c * 4 + 1) * 68 + t] = av.y;
        aT[(1 + c * 4 + 2) * 68 + t] = av.z; aT[(1 + c * 4 + 3) * 68 + t] = av.w;
        vT[(1 + c * 4 + 0) * 68 + t] = vv.x; vT[(1 + c * 4 + 1) * 68 + t] = vv.y;
        vT[(1 + c * 4 + 2) * 68 + t] = vv.z; vT[(1 + c * 4 + 3) * 68 + t] = vv.w;
    }
    for (int idx = tid; idx < 1536; idx += 512) {    // 64 t * 24 float4
        int t = idx / 24, c = idx - t * 24;
        float4 xv = *(const float4*)&text[(b * 64 + t) * 96 + c * 4];
        xT[(1 + c * 4 + 0) * 72 + t] = f2bf(xv.x);
        xT[(1 + c * 4 + 1) * 72 + t] = f2bf(xv.y);
        xT[(1 + c * 4 + 2) * 72 + t] = f2bf(xv.z);
        xT[(1 + c * 4 + 3) * 72 + t] = f2bf(xv.w);
    }
    if (tid < 64) {                                  // ones rows + zero pad rows
        aT[tid] = 1.0f; vT[tid] = 1.0f; xT[tid] = 0x3F80;
        for (int k = 97; k < 112; ++k) xT[k * 72 + tid] = 0;
    }
    __syncthreads();

    const int wave = tid >> 6, lane = tid & 63;
    const int q = lane >> 4, ln = lane & 15;

    // each wave: one 16-ij tile; ij0 = g*128 + wave*16
    {
        const int ij0 = g * 128 + wave * 16;
        const int ij = ij0 + ln;
        const bool valid = ij < IJ;
        const int ijc = valid ? ij : IJ - 1;
        const int i = ijc / 49, j2 = ijc - i * 49;
        const float* ar = &aT[i * 68 + q * 8];
        const float* vr = &vT[j2 * 68 + q * 8];

        s8v af0, af1;
        #pragma unroll
        for (int j = 0; j < 8; ++j) {
            float w0 = ar[j] * vr[j];
            float w1 = ar[32 + j] * vr[32 + j];
            ((unsigned short*)&af0)[j] = valid ? f2bf(w0) : (unsigned short)0;
            ((unsigned short*)&af1)[j] = valid ? f2bf(w1) : (unsigned short)0;
        }
        #pragma unroll
        for (int nt = 0; nt < 7; ++nt) {
            s8v bf0 = *(const s8v*)&xT[(nt * 16 + ln) * 72 + q * 8];
            s8v bf1 = *(const s8v*)&xT[(nt * 16 + ln) * 72 + 32 + q * 8];
            f4v acc = {0.f, 0.f, 0.f, 0.f};
            acc = __builtin_amdgcn_mfma_f32_16x16x32_bf16(af0, bf0, acc, 0, 0, 0);
            acc = __builtin_amdgcn_mfma_f32_16x16x32_bf16(af1, bf1, acc, 0, 0, 0);
            int kk = nt * 16 + ln;           // C: col=ln -> kk, row=q*4+r -> ij
            if (kk < X1) {
                #pragma unroll
                for (int r = 0; r < 4; ++r)
                    out_s[(wave * 16 + q * 4 + r) * 97 + kk] = f2bf(acc[r]);
            }
        }
    }
    __syncthreads();

    // drain: group p-range = [g*12416, g*12416+12416) = 388 aligned 32-chunks.
    // slot s (0..1551): 8 shorts at out_s + s*8; dest chunk = s>>2, lane16 = s&3.
    const size_t gbase = (size_t)(g * 388) * (128 * 32) + (size_t)b * 32;
    for (int s = tid; s < 1552; s += 512) {
        u8sv v = *(const u8sv*)&out_s[s * 8];
        *(u8sv*)&fusionT[gbase + (size_t)(s >> 2) * 4096 + (s & 3) * 8] = v;
    }
}

// ---------------- k2: split-K GEMM, coalesced + register prefetch -------
// 461 blocks x 512 thr (8 waves). Wave owns f = wave*16+ln; all M=128.
// A-frag: contiguous 1KB per (m-tile, step) across the wave.
template<bool GUARD>
__device__ __forceinline__ void k2_body(
    const unsigned short* __restrict__ fusionT, const float* __restrict__ W1,
    float* __restrict__ partials, int blk)
{
    const int tid = threadIdx.x;
    const int wave = tid >> 6, lane = tid & 63;
    const int q = lane >> 4, ln = lane & 15;
    const int f = wave * 16 + ln;
    const int kbase = blk * KC;

    const unsigned short* aptr = fusionT + (size_t)(blk * 16) * 4096 + ln * 32 + q * 8;

    f4v acc[8];
    #pragma unroll
    for (int m = 0; m < 8; ++m) acc[m] = (f4v){0.f, 0.f, 0.f, 0.f};

    s8v a_cur[8], a_nxt[8];
    float bw_cur[8], bw_nxt[8];

    #pragma unroll
    for (int j = 0; j < 8; ++j) {
        int p = kbase + q * 8 + j;
        if (GUARD) bw_cur[j] = (p < KTOT) ? W1[(size_t)p * PF + f] : 0.f;
        else       bw_cur[j] = __builtin_nontemporal_load(&W1[(size_t)p * PF + f]);
    }
    #pragma unroll
    for (int m = 0; m < 8; ++m)
        a_cur[m] = *(const s8v*)(aptr + m * 512);

    #pragma unroll
    for (int s = 0; s < 16; ++s) {
        if (s < 15) {
            const int p0 = kbase + (s + 1) * 32 + q * 8;
            #pragma unroll
            for (int j = 0; j < 8; ++j) {
                if (GUARD) bw_nxt[j] = (p0 + j < KTOT) ? W1[(size_t)(p0 + j) * PF + f] : 0.f;
                else       bw_nxt[j] = __builtin_nontemporal_load(&W1[(size_t)(p0 + j) * PF + f]);
            }
            #pragma unroll
            for (int m = 0; m < 8; ++m)
                a_nxt[m] = *(const s8v*)(aptr + (s + 1) * 4096 + m * 512);
        }
        s8v bf;
        #pragma unroll
        for (int j = 0; j < 8; ++j)
            ((unsigned short*)&bf)[j] = f2bf(bw_cur[j]);
        #pragma unroll
        for (int m = 0; m < 8; ++m)
            acc[m] = __builtin_amdgcn_mfma_f32_16x16x32_bf16(a_cur[m], bf, acc[m], 0, 0, 0);
        #pragma unroll
        for (int m = 0; m < 8; ++m) a_cur[m] = a_nxt[m];
        #pragma unroll
        for (int j = 0; j < 8; ++j) bw_cur[j] = bw_nxt[j];
    }

    float* outp = partials + (size_t)blk * 16384;
    #pragma unroll
    for (int m = 0; m < 8; ++m)
        #pragma unroll
        for (int r = 0; r < 4; ++r)
            outp[(m * 16 + q * 4 + r) * 128 + f] = acc[m][r];
}

__global__ __launch_bounds__(512, 4) void k2_gemm(
    const unsigned short* __restrict__ fusionT, const float* __restrict__ W1,
    float* __restrict__ partials)
{
    const int blk = blockIdx.x;
    // blocks 454..460 touch p >= KTOT (zero-padded fusion rows / OOB W1): guard.
    if (blk >= 454) k2_body<true>(fusionT, W1, partials, blk);
    else            k2_body<false>(fusionT, W1, partials, blk);
}

// ---------------- k3: reduce partials + bias + relu ---------------------
__global__ __launch_bounds__(256) void k3_reduce(
    const float* __restrict__ partials, const float* __restrict__ b1,
    float* __restrict__ h1)
{
    __shared__ float red[256];
    const int e = blockIdx.x * 32 + (threadIdx.x & 31);
    const int rh = threadIdx.x >> 5;           // 0..7
    float s0 = 0.f, s1 = 0.f;
    int r = rh;
    for (; r + 8 < NB2; r += 16) {
        s0 += partials[(size_t)r * 16384 + e];
        s1 += partials[(size_t)(r + 8) * 16384 + e];
    }
    for (; r < NB2; r += 8) s0 += partials[(size_t)r * 16384 + e];
    red[threadIdx.x] = s0 + s1;
    __syncthreads();
    if (threadIdx.x < 32) {
        float v = 0.f;
        #pragma unroll
        for (int g = 0; g < 8; ++g) v += red[g * 32 + threadIdx.x];
        v += b1[e & 127];
        h1[e] = fmaxf(v, 0.f);
    }
}

// ---------------- k45: out = sigmoid(relu(h1@W2+b2)@W3 + b3)*6 - 3 ------
__global__ __launch_bounds__(128) void k45_tail(
    const float* __restrict__ h1, const float* __restrict__ W2,
    const float* __restrict__ b2, const float* __restrict__ W3,
    const float* __restrict__ b3, float* __restrict__ out)
{
    __shared__ float hrow[128];
    __shared__ float h2s[128];
    const int b = blockIdx.x, f = threadIdx.x;
    hrow[f] = h1[b * 128 + f];
    __syncthreads();
    float s = b2[f];
    #pragma unroll 8
    for (int c = 0; c < 128; ++c) s += hrow[c] * W2[c * 128 + f];
    h2s[f] = fmaxf(s, 0.f) * W3[f];
    __syncthreads();
    if (f < 64) {
        float v = h2s[f] + h2s[f + 64];
        #pragma unroll
        for (int off = 32; off > 0; off >>= 1)
            v += __shfl_down(v, off, 64);
        if (f == 0) out[b] = 6.0f / (1.0f + expf(-(v + b3[0]))) - 3.0f;
    }
}

extern "C" void kernel_launch(void* const* d_in, const int* in_sizes, int n_in,
                              void* d_out, int out_size, void* d_ws, size_t ws_size,
                              hipStream_t stream)
{
    const float* audio = (const float*)d_in[0];
    const float* video = (const float*)d_in[1];
    const float* text  = (const float*)d_in[2];
    const float* W1 = (const float*)d_in[3];
    const float* b1 = (const float*)d_in[4];
    const float* W2 = (const float*)d_in[5];
    const float* b2 = (const float*)d_in[6];
    const float* W3 = (const float*)d_in[7];
    const float* b3 = (const float*)d_in[8];
    float* out = (float*)d_out;

    // ws layout (bytes):
    //   fusionT bf16 [7376][128][32] @ 0          = 60,424,192
    //   partials fp32 [461][16384]   @ 60,424,192 = 30,212,096
    //   h1 fp32 [16384]              @ 90,636,288
    char* ws = (char*)d_ws;
    unsigned short* fusionT = (unsigned short*)ws;
    float* partials = (float*)(ws + 60424192);
    float* h1 = (float*)(ws + 90636288);

    k1_fusion<<<dim3(NGRP, 128), 512, 0, stream>>>(audio, video, text, fusionT);
    k2_gemm<<<dim3(NB2), 512, 0, stream>>>(fusionT, W1, partials);
    k3_reduce<<<dim3(512), 256, 0, stream>>>(partials, b1, h1);
    k45_tail<<<dim3(128), 128, 0, stream>>>(h1, W2, b2, W3, b3, out);
}